// Round 15
// baseline (54.807 us; speedup 1.0000x reference)
//
#include <hip/hip_runtime.h>
#include <stdint.h>

// KeepTopN: inputs (32, 56, 56, 256) f32, n = 48 (k-th largest per row).
// v15: PURE streams only; write moved to the end and fused with scatter.
//   k_spec       : pure-READ candidate scan (positions of x > TG into
//                  per-block slots). No output writes.
//   k_sel        : exact radix-select over candidate keys -> thr[row],
//                  flag[row]. No output writes. Full-row fallback radix
//                  (flag=0) if speculation failed (never on N(0,1)).
//   k_fillscatter: per-tile pure-WRITE zero-fill (plain stores, fill-shaped)
//                  + barrier + scatter of the tile's slot survivors v>=thr.
//                  flag==0 tile: masked full re-read+write (correct always).
#define ROWS 32
#define ROW_LEN 802816      // 56*56*256
#define ROW_LEN4 200704     // ROW_LEN / 4
#define BPR 98              // blocks per row
#define F4_PER_BLOCK 2048
#define THREADS 256
#define F4_PER_THREAD 8     // 2048 / 256
#define TG 3.0f             // speculative threshold; E[cand/row] ~= 1084
#define BCAP 40             // per-block candidate slots (mean ~11)
#define CAP_ROW (BPR * BCAP)   // 3920
#define SLOTS_PT 16            // ceil(3920/256)

// ws layout (bytes), ~515 KB (proven):
//   cand : u32[ROWS][BPR][BCAP] @ 0       (501760)  element index within row
//   bcnt : i32[ROWS*BPR]        @ 501760  (12544)   always fully rewritten
//   thr  : f32[ROWS]            @ 514304  (128)     always fully rewritten
//   flag : i32[ROWS]            @ 514432  (128)     always fully rewritten
#define OFF_BCNT 501760
#define OFF_THR  514304
#define OFF_FLAG 514432

// Monotone order-preserving f32 -> u32 key (larger float -> larger key).
__device__ __forceinline__ uint32_t fkey(float x) {
    uint32_t u = __float_as_uint(x);
    return (u & 0x80000000u) ? ~u : (u | 0x80000000u);
}
__device__ __forceinline__ float fkey_inv(uint32_t k) {
    uint32_t u = (k & 0x80000000u) ? (k & 0x7FFFFFFFu) : ~k;
    return __uint_as_float(u);
}

// Pass 1: PURE READ. Stream input, record positions of values > TG.
__global__ __launch_bounds__(THREADS) void k_spec(const float* __restrict__ in,
                                                  uint32_t* __restrict__ cand,
                                                  int* __restrict__ bcnt) {
    __shared__ uint32_t lp[BCAP];
    __shared__ int lcnt;
    const int row = blockIdx.x / BPR;
    const int blk = blockIdx.x % BPR;
    if (threadIdx.x == 0) lcnt = 0;
    __syncthreads();
    const float4* p = (const float4*)in + (size_t)row * ROW_LEN4
                      + (size_t)blk * F4_PER_BLOCK + threadIdx.x;
    float4 d[F4_PER_THREAD];
#pragma unroll
    for (int v = 0; v < F4_PER_THREAD; ++v) d[v] = p[v * THREADS];
#pragma unroll
    for (int v = 0; v < F4_PER_THREAD; ++v) {
        const float mx = fmaxf(fmaxf(d[v].x, d[v].y), fmaxf(d[v].z, d[v].w));
        if (__any(mx > TG)) {
            const uint32_t e = (uint32_t)(blk * F4_PER_BLOCK + v * THREADS + threadIdx.x) * 4u;
            if (d[v].x > TG) { int j = atomicAdd(&lcnt, 1); if (j < BCAP) lp[j] = e + 0u; }
            if (d[v].y > TG) { int j = atomicAdd(&lcnt, 1); if (j < BCAP) lp[j] = e + 1u; }
            if (d[v].z > TG) { int j = atomicAdd(&lcnt, 1); if (j < BCAP) lp[j] = e + 2u; }
            if (d[v].w > TG) { int j = atomicAdd(&lcnt, 1); if (j < BCAP) lp[j] = e + 3u; }
        }
    }
    __syncthreads();
    const int c = lcnt;
    if (threadIdx.x == 0) bcnt[row * BPR + blk] = c;  // raw; overflow -> fallback
    const int cc = c < BCAP ? c : BCAP;
    for (int i = threadIdx.x; i < cc; i += THREADS)
        cand[((size_t)row * BPR + blk) * BCAP + i] = lp[i];
}

// Parallel digit pick: histogram h[256] -> inclusive suffix scan across the
// 256 threads (Hillis-Steele, 8 steps) -> digit d with S[d] >= r > S[d+1].
__device__ __forceinline__ void pick_digit(uint32_t* h, int t, int r,
                                           int* sh_sel, int* sh_rank) {
#pragma unroll
    for (int off = 1; off < 256; off <<= 1) {
        uint32_t v = h[t] + ((t + off < 256) ? h[t + off] : 0u);
        __syncthreads();
        h[t] = v;
        __syncthreads();
    }
    const uint32_t Sd = h[t];
    const uint32_t Sd1 = (t < 255) ? h[t + 1] : 0u;
    if ((int)Sd >= r && (int)Sd1 < r) { *sh_sel = t; *sh_rank = r - (int)Sd1; }
    __syncthreads();
}

// Pass 2: per row: gather candidate keys (input L3-resident), exact 4x8-bit
// radix select -> thr[row], flag[row]=1. Fallback: full-row radix, flag=0.
__global__ __launch_bounds__(THREADS) void k_sel(const float* __restrict__ in,
                                                 const int* __restrict__ n_ptr,
                                                 const int* __restrict__ bcnt,
                                                 const uint32_t* __restrict__ cand,
                                                 float* __restrict__ thr,
                                                 int* __restrict__ flag) {
    __shared__ int lb[BPR];
    __shared__ uint32_t h[256];
    __shared__ int sh_sel, sh_rank, sh_m, sh_bad;
    const int row = blockIdx.x;
    const int t = threadIdx.x;
    const int n = *n_ptr;
    const float* rin = in + (size_t)row * ROW_LEN;

    if (t == 0) { sh_m = 0; sh_bad = 0; }
    __syncthreads();
    {
        int lsum = 0, lbad = 0;
        for (int b = t; b < BPR; b += THREADS) {
            const int c = bcnt[row * BPR + b];
            lbad |= (c > BCAP);
            const int cc = c < BCAP ? c : BCAP;
            lb[b] = cc;
            lsum += cc;
        }
        if (lsum) atomicAdd(&sh_m, lsum);
        if (lbad) atomicOr(&sh_bad, 1);
    }
    __syncthreads();
    const int m = sh_m;
    const bool ok = (!sh_bad) && (m >= n) && (n >= 1);

    if (ok) {
        uint32_t key[SLOTS_PT];
        bool val[SLOTS_PT];
#pragma unroll
        for (int j = 0; j < SLOTS_PT; ++j) {
            const int slot = j * THREADS + t;
            uint32_t k = 0; bool v = false;
            if (slot < CAP_ROW) {
                const int b = slot / BCAP;
                v = (slot - b * BCAP) < lb[b];
                if (v) k = fkey(rin[cand[(size_t)row * CAP_ROW + slot]]);
            }
            key[j] = k; val[j] = v;
        }
        uint32_t prefix = 0, msk = 0;
        int r = n;
        for (int rd = 0; rd < 4; ++rd) {
            const int shn = 24 - rd * 8;
            h[t] = 0;
            __syncthreads();
#pragma unroll
            for (int j = 0; j < SLOTS_PT; ++j)
                if (val[j] && (key[j] & msk) == prefix)
                    atomicAdd(&h[(key[j] >> shn) & 255u], 1u);
            __syncthreads();
            pick_digit(h, t, r, &sh_sel, &sh_rank);
            prefix |= ((uint32_t)sh_sel) << shn;
            msk |= 255u << shn;
            r = sh_rank;
            __syncthreads();
        }
        if (t == 0) { thr[row] = fkey_inv(prefix); flag[row] = 1; }
    } else {
        // Exact fallback: full-row radix select (reads only).
        uint32_t prefix = 0, msk = 0;
        int r = (n < 1) ? 1 : n;
        const float4* p = (const float4*)rin;
        for (int rd = 0; rd < 4; ++rd) {
            const int shn = 24 - rd * 8;
            h[t] = 0;
            __syncthreads();
            for (int i = t; i < ROW_LEN4; i += THREADS) {
                const float4 d = p[i];
                uint32_t k;
                k = fkey(d.x); if ((k & msk) == prefix) atomicAdd(&h[(k >> shn) & 255u], 1u);
                k = fkey(d.y); if ((k & msk) == prefix) atomicAdd(&h[(k >> shn) & 255u], 1u);
                k = fkey(d.z); if ((k & msk) == prefix) atomicAdd(&h[(k >> shn) & 255u], 1u);
                k = fkey(d.w); if ((k & msk) == prefix) atomicAdd(&h[(k >> shn) & 255u], 1u);
            }
            __syncthreads();
            pick_digit(h, t, r, &sh_sel, &sh_rank);
            prefix |= ((uint32_t)sh_sel) << shn;
            msk |= 255u << shn;
            r = sh_rank;
            __syncthreads();
        }
        if (t == 0) { thr[row] = fkey_inv(prefix); flag[row] = 0; }
    }
}

// Pass 3: per tile: PURE WRITE zero-fill + barrier (drains stores) + scatter
// of this tile's slot survivors (v >= thr; all survivors are in slots when
// flag==1 since thr > TG). flag==0: masked full re-read+write (fallback).
__global__ __launch_bounds__(THREADS) void k_fillscatter(const float* __restrict__ in,
                                                         const int* __restrict__ bcnt,
                                                         const uint32_t* __restrict__ cand,
                                                         const float* __restrict__ thr,
                                                         const int* __restrict__ flag,
                                                         float* __restrict__ out) {
    const int row = blockIdx.x / BPR;
    const int blk = blockIdx.x % BPR;
    const float tf = thr[row];
    const size_t base = (size_t)row * ROW_LEN4 + (size_t)blk * F4_PER_BLOCK + threadIdx.x;
    float4* q = (float4*)out + base;
    if (flag[row]) {
        const float4 z = make_float4(0.f, 0.f, 0.f, 0.f);
#pragma unroll
        for (int v = 0; v < F4_PER_THREAD; ++v)
            q[v * THREADS] = z;
        const int c0 = bcnt[row * BPR + blk];
        const int c = c0 < BCAP ? c0 : BCAP;
        __syncthreads();   // compiler drains vmcnt before barrier -> stores ordered
        const float* rin = in + (size_t)row * ROW_LEN;
        float* rout = out + (size_t)row * ROW_LEN;
        for (int i = threadIdx.x; i < c; i += THREADS) {
            const uint32_t pos = cand[((size_t)row * BPR + blk) * BCAP + i];
            const float v = rin[pos];
            if (v >= tf) rout[pos] = v;
        }
    } else {
        // Fallback tile: masked full re-read + write (never taken on N(0,1)).
        const float4* p = (const float4*)in + base;
#pragma unroll
        for (int v = 0; v < F4_PER_THREAD; ++v) {
            float4 d = p[v * THREADS];
            d.x = (d.x >= tf) ? d.x : 0.0f;
            d.y = (d.y >= tf) ? d.y : 0.0f;
            d.z = (d.z >= tf) ? d.z : 0.0f;
            d.w = (d.w >= tf) ? d.w : 0.0f;
            q[v * THREADS] = d;
        }
    }
}

extern "C" void kernel_launch(void* const* d_in, const int* in_sizes, int n_in,
                              void* d_out, int out_size, void* d_ws, size_t ws_size,
                              hipStream_t stream) {
    const float* in = (const float*)d_in[0];
    const int* n_ptr = (const int*)d_in[1];
    float* out = (float*)d_out;
    char* ws = (char*)d_ws;

    uint32_t* cand = (uint32_t*)ws;
    int* bcnt = (int*)(ws + OFF_BCNT);
    float* thr = (float*)(ws + OFF_THR);
    int* flag = (int*)(ws + OFF_FLAG);

    k_spec<<<ROWS * BPR, THREADS, 0, stream>>>(in, cand, bcnt);
    k_sel<<<ROWS, THREADS, 0, stream>>>(in, n_ptr, bcnt, cand, thr, flag);
    k_fillscatter<<<ROWS * BPR, THREADS, 0, stream>>>(in, bcnt, cand, thr, flag, out);
}

// Round 16
// 51.511 us; speedup vs baseline: 1.0640x; 1.0640x over previous
//
#include <hip/hip_runtime.h>
#include <stdint.h>

// KeepTopN: inputs (32, 56, 56, 256) f32, n = 48 (k-th largest per row).
// v16 = round-8 winner (fused read + nt zero-store + register detect, then
// parallel radix-select + scatter) with halved tiles: 6272 blocks to cut
// dispatch ramp/tail (Occupancy was 53%). Inline full-row fallback keeps
// correctness unconditional on any data.
#define ROWS 32
#define ROW_LEN 802816      // 56*56*256
#define ROW_LEN4 200704     // ROW_LEN / 4
#define BPR 196             // blocks per row (200704 = 196 * 1024)
#define F4_PER_BLOCK 1024
#define THREADS 256
#define F4_PER_THREAD 4     // 1024 / 256
#define TG 3.0f             // speculative threshold; E[cand/row] ~= 1084
#define BCAP 24             // per-block candidate slots (mean ~5.5)
#define CAP_ROW (BPR * BCAP)   // 4704
#define SLOTS_PT 19            // ceil(4704/256)

// ws layout (bytes), ~615 KB:
//   cand : u32[ROWS][BPR][BCAP] @ 0       (602112)  element index within row
//   bcnt : i32[ROWS*BPR]        @ 602112  (25088)   always fully rewritten
//   thr  : f32[ROWS]            @ 627200  (128)
#define OFF_BCNT 602112
#define OFF_THR  627200

typedef float f32x4 __attribute__((ext_vector_type(4)));  // for nt store

// Monotone order-preserving f32 -> u32 key (larger float -> larger key).
__device__ __forceinline__ uint32_t fkey(float x) {
    uint32_t u = __float_as_uint(x);
    return (u & 0x80000000u) ? ~u : (u | 0x80000000u);
}
__device__ __forceinline__ float fkey_inv(uint32_t k) {
    uint32_t u = (k & 0x80000000u) ? (k & 0x7FFFFFFFu) : ~k;
    return __uint_as_float(u);
}

// Pass 1: fused stream: read input, nt-store zeros to out, record positions
// of values > TG into this block's private slots (register detect + __any).
__global__ __launch_bounds__(THREADS) void k_spec(const float* __restrict__ in,
                                                  float* __restrict__ out,
                                                  uint32_t* __restrict__ pos,
                                                  int* __restrict__ bcnt) {
    __shared__ uint32_t lp[BCAP];
    __shared__ int lcnt;
    const int row = blockIdx.x / BPR;
    const int blk = blockIdx.x % BPR;
    if (threadIdx.x == 0) lcnt = 0;
    __syncthreads();
    const size_t base = (size_t)row * ROW_LEN4 + (size_t)blk * F4_PER_BLOCK + threadIdx.x;
    const float4* p = (const float4*)in + base;
    f32x4* q = (f32x4*)out + base;
    const f32x4 z = {0.f, 0.f, 0.f, 0.f};

    float4 d[F4_PER_THREAD];
#pragma unroll
    for (int v = 0; v < F4_PER_THREAD; ++v) d[v] = p[v * THREADS];
#pragma unroll
    for (int v = 0; v < F4_PER_THREAD; ++v)
        __builtin_nontemporal_store(z, q + v * THREADS);
#pragma unroll
    for (int v = 0; v < F4_PER_THREAD; ++v) {
        const float mx = fmaxf(fmaxf(d[v].x, d[v].y), fmaxf(d[v].z, d[v].w));
        if (__any(mx > TG)) {
            const uint32_t e = (uint32_t)(blk * F4_PER_BLOCK + v * THREADS + threadIdx.x) * 4u;
            if (d[v].x > TG) { int j = atomicAdd(&lcnt, 1); if (j < BCAP) lp[j] = e + 0u; }
            if (d[v].y > TG) { int j = atomicAdd(&lcnt, 1); if (j < BCAP) lp[j] = e + 1u; }
            if (d[v].z > TG) { int j = atomicAdd(&lcnt, 1); if (j < BCAP) lp[j] = e + 2u; }
            if (d[v].w > TG) { int j = atomicAdd(&lcnt, 1); if (j < BCAP) lp[j] = e + 3u; }
        }
    }
    __syncthreads();
    const int c = lcnt;
    if (threadIdx.x == 0) bcnt[row * BPR + blk] = c;  // raw (overflow detected later)
    const int cc = c < BCAP ? c : BCAP;
    for (int i = threadIdx.x; i < cc; i += THREADS)
        pos[((size_t)row * BPR + blk) * BCAP + i] = lp[i];
}

// Parallel digit pick: histogram h[256] -> inclusive suffix scan across the
// 256 threads (Hillis-Steele, 8 steps) -> digit d with S[d] >= r > S[d+1].
__device__ __forceinline__ void pick_digit(uint32_t* h, int t, int r,
                                           int* sh_sel, int* sh_rank) {
#pragma unroll
    for (int off = 1; off < 256; off <<= 1) {
        uint32_t v = h[t] + ((t + off < 256) ? h[t + off] : 0u);
        __syncthreads();
        h[t] = v;
        __syncthreads();
    }
    const uint32_t Sd = h[t];
    const uint32_t Sd1 = (t < 255) ? h[t + 1] : 0u;
    if ((int)Sd >= r && (int)Sd1 < r) { *sh_sel = t; *sh_rank = r - (int)Sd1; }
    __syncthreads();
}

// Pass 2: per row: gather candidate keys (cache-resident input), exact
// 4x8-bit radix select of the n-th largest, scatter survivors into the
// zeroed output. Fallback (!ok): full-row radix + full-row masked write.
__global__ __launch_bounds__(THREADS) void k_sel(const float* __restrict__ in,
                                                 const int* __restrict__ n_ptr,
                                                 const int* __restrict__ bcnt,
                                                 const uint32_t* __restrict__ pos,
                                                 float* __restrict__ out,
                                                 float* __restrict__ thr) {
    __shared__ int lb[BPR];
    __shared__ uint32_t h[256];
    __shared__ int sh_sel, sh_rank, sh_m, sh_bad;
    const int row = blockIdx.x;
    const int t = threadIdx.x;
    const int n = *n_ptr;
    const float* rin = in + (size_t)row * ROW_LEN;
    float* rout = out + (size_t)row * ROW_LEN;

    if (t == 0) { sh_m = 0; sh_bad = 0; }
    __syncthreads();
    {
        int lsum = 0, lbad = 0;
        for (int b = t; b < BPR; b += THREADS) {
            const int c = bcnt[row * BPR + b];
            lbad |= (c > BCAP);
            const int cc = c < BCAP ? c : BCAP;
            lb[b] = cc;
            lsum += cc;
        }
        if (lsum) atomicAdd(&sh_m, lsum);
        if (lbad) atomicOr(&sh_bad, 1);
    }
    __syncthreads();
    const int m = sh_m;
    const bool ok = (!sh_bad) && (m >= n) && (n >= 1);

    if (ok) {
        // Coalesced slot load + gathered key fetch (cache-resident input).
        uint32_t key[SLOTS_PT];
        uint32_t ps[SLOTS_PT];
        bool val[SLOTS_PT];
#pragma unroll
        for (int j = 0; j < SLOTS_PT; ++j) {
            const int slot = j * THREADS + t;
            uint32_t k = 0, pp = 0; bool v = false;
            if (slot < CAP_ROW) {
                const int b = slot / BCAP;
                v = (slot - b * BCAP) < lb[b];
                if (v) {
                    pp = pos[(size_t)row * CAP_ROW + slot];
                    k = fkey(rin[pp]);
                }
            }
            key[j] = k; ps[j] = pp; val[j] = v;
        }
        uint32_t prefix = 0, msk = 0;
        int r = n;
        for (int rd = 0; rd < 4; ++rd) {
            const int shn = 24 - rd * 8;
            h[t] = 0;
            __syncthreads();
#pragma unroll
            for (int j = 0; j < SLOTS_PT; ++j)
                if (val[j] && (key[j] & msk) == prefix)
                    atomicAdd(&h[(key[j] >> shn) & 255u], 1u);
            __syncthreads();
            pick_digit(h, t, r, &sh_sel, &sh_rank);
            prefix |= ((uint32_t)sh_sel) << shn;
            msk |= 255u << shn;
            r = sh_rank;
            __syncthreads();
        }
        // Scatter survivors (key >= prefix <=> value >= threshold).
#pragma unroll
        for (int j = 0; j < SLOTS_PT; ++j)
            if (val[j] && key[j] >= prefix)
                rout[ps[j]] = fkey_inv(key[j]);
        if (t == 0) thr[row] = fkey_inv(prefix);
    } else {
        // Exact fallback: full-row radix select + full-row masked write.
        uint32_t prefix = 0, msk = 0;
        int r = (n < 1) ? 1 : n;
        const float4* p = (const float4*)rin;
        for (int rd = 0; rd < 4; ++rd) {
            const int shn = 24 - rd * 8;
            h[t] = 0;
            __syncthreads();
            for (int i = t; i < ROW_LEN4; i += THREADS) {
                const float4 d = p[i];
                uint32_t k;
                k = fkey(d.x); if ((k & msk) == prefix) atomicAdd(&h[(k >> shn) & 255u], 1u);
                k = fkey(d.y); if ((k & msk) == prefix) atomicAdd(&h[(k >> shn) & 255u], 1u);
                k = fkey(d.z); if ((k & msk) == prefix) atomicAdd(&h[(k >> shn) & 255u], 1u);
                k = fkey(d.w); if ((k & msk) == prefix) atomicAdd(&h[(k >> shn) & 255u], 1u);
            }
            __syncthreads();
            pick_digit(h, t, r, &sh_sel, &sh_rank);
            prefix |= ((uint32_t)sh_sel) << shn;
            msk |= 255u << shn;
            r = sh_rank;
            __syncthreads();
        }
        const float tf = fkey_inv(prefix);
        float4* q = (float4*)rout;
        for (int i = t; i < ROW_LEN4; i += THREADS) {
            float4 d = p[i];
            d.x = (d.x >= tf) ? d.x : 0.0f;
            d.y = (d.y >= tf) ? d.y : 0.0f;
            d.z = (d.z >= tf) ? d.z : 0.0f;
            d.w = (d.w >= tf) ? d.w : 0.0f;
            q[i] = d;
        }
        if (t == 0) thr[row] = tf;
    }
}

extern "C" void kernel_launch(void* const* d_in, const int* in_sizes, int n_in,
                              void* d_out, int out_size, void* d_ws, size_t ws_size,
                              hipStream_t stream) {
    const float* in = (const float*)d_in[0];
    const int* n_ptr = (const int*)d_in[1];
    float* out = (float*)d_out;
    char* ws = (char*)d_ws;

    uint32_t* pos = (uint32_t*)ws;
    int* bcnt = (int*)(ws + OFF_BCNT);
    float* thr = (float*)(ws + OFF_THR);

    k_spec<<<ROWS * BPR, THREADS, 0, stream>>>(in, out, pos, bcnt);
    k_sel<<<ROWS, THREADS, 0, stream>>>(in, n_ptr, bcnt, pos, out, thr);
}